// Round 6
// baseline (31.688 us; speedup 1.0000x reference)
//
#include <hip/hip_runtime.h>
#include <math.h>

#define HH 128
#define WW 128
#define LROWS 36
#define LCOLS 136                 // 34 float4 slots per row (4-col halo each side)
#define LSLOTS (LROWS * 34)       // 1224 float4 slots
#define LFLOATS (LROWS * LCOLS)   // 4896 floats = 19584 B

__device__ __forceinline__ void gload_lds16(const float* gp, float* lp) {
    __builtin_amdgcn_global_load_lds(
        (const __attribute__((address_space(1))) void*)gp,
        (__attribute__((address_space(3))) void*)lp,
        16, 0, 0);
}

__global__ __launch_bounds__(256, 8) void morpho_kernel(
    const float* __restrict__ x,     // [B,C,128,128]
    const float* __restrict__ wgt,   // [B,C,5,5]
    const float* __restrict__ bias,  // [B,C]
    const float* __restrict__ sign,  // [B]
    float* __restrict__ out)         // [B,C,128,128]
{
    __shared__ float lds[LFLOATS];

    const int blk  = blockIdx.x;
    const int quad = blk & 3;        // 32-row band of the plane
    const int bc   = blk >> 2;       // plane = b*64 + c
    const int b    = bc >> 6;

    const float* __restrict__ xp = x   + (size_t)bc * (HH * WW);
    float*       __restrict__ yp = out + (size_t)bc * (HH * WW);
    const float* __restrict__ wp = wgt + bc * 25;

    const float sgn = sign[b];
    const float s   = (fabsf(sgn) >= 1e-7f) ? sgn : 1.0f;
    const float bvs = bias[bc] * s;

    const int t = threadIdx.x;
    const float4 z4 = make_float4(0.f, 0.f, 0.f, 0.f);

    // ---- zero the pad slots directly (masked gloads below never touch them) ----
    if (t < 72) {                        // col halos: slots 0 and 33 of each row
        const int r  = t >> 1;
        const int c4 = (t & 1) ? 33 : 0;
        *reinterpret_cast<float4*>(&lds[(r * 34 + c4) * 4]) = z4;
    }
    if (quad == 0 && t < 68) {           // LDS rows 0,1 = input rows -2,-1
        *reinterpret_cast<float4*>(&lds[t * 4]) = z4;
    }
    if (quad == 3 && t < 68) {           // LDS rows 34,35 = input rows 128,129
        *reinterpret_cast<float4*>(&lds[(34 * 34 + t) * 4]) = z4;
    }

    // ---- stage: exec-masked global_load_lds of raw x (no clamps, no fixup) ----
    const int rowbase = quad * 32 - 2;
#pragma unroll
    for (int k = 0; k < 5; ++k) {
        const int i = k * 256 + t;
        if (i < LSLOTS) {
            const int r    = i / 34;
            const int c4   = i - r * 34;
            const int grow = rowbase + r;
            const bool valid = (c4 >= 1) && (c4 <= 32) &&
                               (grow >= 0) && (grow < HH);
            if (valid) {
                // LDS dest: wave-uniform base + lane*16 (slots are wave-contiguous)
                gload_lds16(xp + grow * WW + (c4 * 4 - 4),
                            &lds[(k * 256 + (t & 192)) * 4]);
            }
        }
    }

    float wv[25];                        // block-uniform -> SGPRs
#pragma unroll
    for (int k = 0; k < 25; ++k) wv[k] = wp[k];

    __syncthreads();

    // ---- compute: 4 rows x 4 cols per thread, LDS via one base + imm offsets ----
    const int tx = t & 31;
    const int ty = t >> 5;
    const float* lbase = &lds[(ty * 4) * LCOLS + tx * 4];

    float acc[4][4];                     // first-touch at p==0
#pragma unroll
    for (int r8 = 0; r8 < 8; ++r8) {
        const float* lp = lbase + r8 * LCOLS;
        const float4 a0 = *reinterpret_cast<const float4*>(lp);
        const float4 a1 = *reinterpret_cast<const float4*>(lp + 4);
        const float4 a2 = *reinterpret_cast<const float4*>(lp + 8);
        float xr[12] = {a0.x, a0.y, a0.z, a0.w,
                        a1.x, a1.y, a1.z, a1.w,
                        a2.x, a2.y, a2.z, a2.w};
#pragma unroll
        for (int p = 0; p < 5; ++p) {
            const int oi = r8 - p;       // output row fed by this input row
            if (oi >= 0 && oi < 4) {
#pragma unroll
                for (int oj = 0; oj < 4; ++oj) {
                    // tap = x*s + w; pad x==0 -> w (matches zero-padded scaled x)
                    const float t0 = fmaf(xr[oj + 2], s, wv[p * 5 + 0]);
                    const float t1 = fmaf(xr[oj + 3], s, wv[p * 5 + 1]);
                    const float t2 = fmaf(xr[oj + 4], s, wv[p * 5 + 2]);
                    const float t3 = fmaf(xr[oj + 5], s, wv[p * 5 + 3]);
                    const float t4 = fmaf(xr[oj + 6], s, wv[p * 5 + 4]);
                    float m;
                    if (p == 0) {
                        m = fmaxf(fmaxf(t0, t1), t2);   // v_max3
                        m = fmaxf(fmaxf(m, t3), t4);    // v_max3
                    } else {
                        m = acc[oi][oj];
                        m = fmaxf(fmaxf(m, t0), t1);
                        m = fmaxf(fmaxf(m, t2), t3);
                        m = fmaxf(m, t4);
                    }
                    acc[oi][oj] = m;
                }
            }
        }
    }

    const int i0 = quad * 32 + ty * 4;
#pragma unroll
    for (int a = 0; a < 4; ++a) {
        float4 o;
        o.x = fmaf(acc[a][0], s, bvs);   // (acc + bias) * s
        o.y = fmaf(acc[a][1], s, bvs);
        o.z = fmaf(acc[a][2], s, bvs);
        o.w = fmaf(acc[a][3], s, bvs);
        *reinterpret_cast<float4*>(yp + (size_t)(i0 + a) * WW + tx * 4) = o;
    }
}

extern "C" void kernel_launch(void* const* d_in, const int* in_sizes, int n_in,
                              void* d_out, int out_size, void* d_ws, size_t ws_size,
                              hipStream_t stream) {
    (void)d_ws; (void)ws_size; (void)in_sizes; (void)n_in; (void)out_size;
    const float* x    = (const float*)d_in[0];
    const float* w    = (const float*)d_in[1];
    const float* bias = (const float*)d_in[2];
    const float* sign = (const float*)d_in[3];
    float* out = (float*)d_out;

    morpho_kernel<<<4096, 256, 0, stream>>>(x, w, bias, sign, out);
}